// Round 2
// baseline (183.687 us; speedup 1.0000x reference)
//
#include <hip/hip_runtime.h>

// CapsuleLayer dynamic routing, MI355X fp32.
// x: [B=64, N=2048, I=8], W: [J=32, N=2048, D=16, I=8], out v: [B=64, J=32, D=16]
//
// R7: R5 + software-pipelined routing loop ONLY (R6's Wt relayout dropped:
// 50 MB workspace is the prime suspect for the container abort — back to the
// proven 16.9 MB footprint). Pipeline: softmax(n) overlapped with
// compute_u(n+1)+logits(n+1), double-buffered lmat/cmat -> ONE barrier per n
// (was two), exp/DPP/ds_swizzle latency hidden under ~90 pk_fma instrs.

#define BB_ 64
#define NN_ 2048
#define II_ 8
#define JJ_ 32
#define DD_ 16
#define NCHUNKS 128
#define CHUNK 16      /* n's per block */
#define BG 8          /* b's per block */
#define NBG (BB_ / BG) /* 8 */
#define EPS_ 1e-7f

#define PARTIAL_FLOATS (NCHUNKS * BB_ * JJ_ * DD_) /* 4M floats = 16.8 MB */

typedef __attribute__((ext_vector_type(2))) float v2f;

// DPP helpers (VALU-pipe cross-lane). CTRL must be an immediate.
template <int CTRL>
__device__ __forceinline__ float dpp_add(float v) {
  const int s = __builtin_amdgcn_update_dpp(
      0, __builtin_bit_cast(int, v), CTRL, 0xf, 0xf, true);
  return v + __builtin_bit_cast(float, s);
}
#define DPP_QP_XOR1 0xB1      /* quad_perm [1,0,3,2]  : lane ^ 1 */
#define DPP_QP_XOR2 0x4E      /* quad_perm [2,3,0,1]  : lane ^ 2 */
#define DPP_HALF_MIRROR 0x141 /* mirror within 8      : lane ^ 7 */
#define DPP_ROR8 0x128        /* row_ror:8 (16-lane)  : lane ^ 8 */

struct W8 {
  v2f k[8];  // k[i] = {W[j][n][2p][i], W[j][n][2p+1][i]} -- pk operands
};

// Load 16 consecutive floats (d-pair {2p,2p+1}, all 8 i's) and pack into pk
// pairs immediately; the raw float4 temps die here (keeps live set <=128 VGPR
// so __launch_bounds__(256,4) holds without spills).
__device__ __forceinline__ W8 loadW(const float* p) {
  const float4* q = (const float4*)p;
  const float4 t0 = q[0], t1 = q[1], t2 = q[2], t3 = q[3];
  W8 w = {{{t0.x, t2.x}, {t0.y, t2.y},
           {t0.z, t2.z}, {t0.w, t2.w},
           {t1.x, t3.x}, {t1.y, t3.y},
           {t1.z, t3.z}, {t1.w, t3.w}}};
  return w;
}

// u[b] = {u_hat[b][j][n][2p], u_hat[b][j][n][2p+1]}; x row is wave-uniform
// (b, n uniform across lanes -> scalar-load path, no LDS).
__device__ __forceinline__ void compute_u(const W8& w, const float* __restrict__ x,
                                          int b0, int n, v2f (&u)[BG]) {
#pragma unroll
  for (int b = 0; b < BG; ++b) {
    const float4* __restrict__ xr =
        (const float4*)(x + ((size_t)(b0 + b) * NN_ + n) * II_);
    const float4 xa = xr[0];
    const float4 xb = xr[1];
    v2f acc = w.k[0] * xa.x;
    acc += w.k[1] * xa.y;
    acc += w.k[2] * xa.z;
    acc += w.k[3] * xa.w;
    acc += w.k[4] * xb.x;
    acc += w.k[5] * xb.y;
    acc += w.k[6] * xb.z;
    acc += w.k[7] * xb.w;
    u[b] = acc;
  }
}

// logits l[b][j] = sum_d u_hat*V: 2-elem partial per lane, xor butterfly over
// the 8 p-lanes, p==0 lane deposits into lrow.
__device__ __forceinline__ void logits_to_lds(const v2f (&u)[BG],
                                              const v2f (&vv)[BG],
                                              float (*lrow)[JJ_], int j, int p) {
#pragma unroll
  for (int b = 0; b < BG; ++b) {
    const v2f m = u[b] * vv[b];
    float lp = m.x + m.y;
    lp = dpp_add<DPP_QP_XOR1>(lp);
    lp = dpp_add<DPP_QP_XOR2>(lp);
    lp = dpp_add<DPP_HALF_MIRROR>(lp);
    if (p == 0) lrow[b][j] = lp;
  }
}

// softmax over j (32 entries) x 8 b; 256 threads handle 1 entry each.
// |logit| <= ~3: exp safe without max subtraction (validated R2/R4).
__device__ __forceinline__ void softmax_step(const float (*lrow)[JJ_],
                                             float (*crow)[JJ_], int tid) {
  const int jj = tid & 31;
  const int bb = tid >> 5;  // 8 b's x 32 j's = 256 threads exactly
  const float e0 = __expf(lrow[bb][jj]);
  float m0 = e0;
  m0 = dpp_add<DPP_QP_XOR1>(m0);
  m0 = dpp_add<DPP_QP_XOR2>(m0);
  m0 = dpp_add<DPP_HALF_MIRROR>(m0);
  m0 = dpp_add<DPP_ROR8>(m0);
  m0 += __shfl_xor(m0, 16);
  crow[bb][jj] = e0 * __builtin_amdgcn_rcpf(m0);
}

// Phase kernel: 256 threads = (j = tid>>3) x (p = tid&7); thread owns output
// cap j, dims d in {2p,2p+1}, for 8 b's. blockIdx = bg*NCHUNKS + chunk so
// blockIdx%8 == chunk%8 -> all 8 blocks sharing a W chunk-slab (256 KB) land
// on one XCD (16 slabs x 256 KB = 4 MB = one L2).
template <int PHASE>
__global__ __launch_bounds__(256, 4) void caps_phase(
    const float* __restrict__ x, const float* __restrict__ W,
    const float* __restrict__ V, float* __restrict__ partial) {
  const int tid = threadIdx.x;
  const int j = tid >> 3;
  const int p = tid & 7;
  const int chunk = blockIdx.x & (NCHUNKS - 1);
  const int bg = blockIdx.x >> 7;
  const int b0 = bg * BG;
  const int n0 = chunk * CHUNK;

  // W[j][n][d][i]: thread reads 16 consecutive floats at j*262144 + n*128 + p*16.
  const float* wp = W + (size_t)j * (NN_ * DD_ * II_) +
                    (size_t)n0 * (DD_ * II_) + (size_t)p * 16;

  v2f s[BG];
#pragma unroll
  for (int b = 0; b < BG; ++b) s[b] = (v2f)(0.f);

  if (PHASE == 0) {
    // softmax(0) over J is uniform -> plain sum (scale at store). No barriers.
    W8 wA = loadW(wp);
    W8 wB = loadW(wp + 128);
    for (int nl = 0; nl < CHUNK; nl += 2) {
      v2f u[BG];
      compute_u(wA, x, b0, n0 + nl, u);
#pragma unroll
      for (int b = 0; b < BG; ++b) s[b] += u[b];
      {
        const int nf = (nl + 2 < CHUNK) ? nl + 2 : CHUNK - 1;
        wA = loadW(wp + (size_t)nf * 128);
      }
      compute_u(wB, x, b0, n0 + nl + 1, u);
#pragma unroll
      for (int b = 0; b < BG; ++b) s[b] += u[b];
      {
        const int nf = (nl + 3 < CHUNK) ? nl + 3 : CHUNK - 1;
        wB = loadW(wp + (size_t)nf * 128);
      }
    }
  } else {
    __shared__ float lmat[2][BG][JJ_];
    __shared__ float cmat[2][BG][JJ_];

    // V fragment: V[b0+b][j][2p..2p+1] for 8 b's.
    v2f vv[BG];
#pragma unroll
    for (int b = 0; b < BG; ++b) {
      const float2 t =
          *(const float2*)&V[((size_t)(b0 + b) * JJ_ + j) * DD_ + 2 * p];
      vv[b] = __builtin_bit_cast(v2f, t);
    }

    // Skewed pipeline, one barrier per n (R5 had two). Steady state:
    //   softmax(n) | compute_u(n+1)+logits(n+1)   [independent: hides the
    //   exp/DPP/ds_swizzle chain under ~90 pk_fma instrs]
    //   barrier;  s += u(n)*c(n)
    // lmat/cmat double-buffered so one barrier covers both the cmat-write ->
    // apply-read and the logits-write -> softmax-read dependencies.
    W8 wA = loadW(wp);
    W8 wB = loadW(wp + 128);
    v2f uA[BG], uB[BG];
    compute_u(wA, x, b0, n0, uA);
    logits_to_lds(uA, vv, lmat[0], j, p);
    __syncthreads();

    for (int nl = 0; nl < CHUNK; nl += 2) {
      // EVEN: softmax n=nl; build n=nl+1; apply c(nl) to uA.
      {
        const int nf = (nl + 2 < CHUNK) ? nl + 2 : CHUNK - 1;
        wA = loadW(wp + (size_t)nf * 128);  // consumed at ODD's compute_u
      }
      softmax_step(lmat[0], cmat[0], tid);
      compute_u(wB, x, b0, n0 + nl + 1, uB);
      logits_to_lds(uB, vv, lmat[1], j, p);
      __syncthreads();
#pragma unroll
      for (int b = 0; b < BG; ++b) s[b] += uA[b] * cmat[0][b][j];

      // ODD: softmax n=nl+1; build n=nl+2 (if any); apply c(nl+1) to uB.
      {
        const int nf = (nl + 3 < CHUNK) ? nl + 3 : CHUNK - 1;
        wB = loadW(wp + (size_t)nf * 128);  // consumed at next EVEN's compute_u
      }
      softmax_step(lmat[1], cmat[1], tid);
      if (nl + 2 < CHUNK) {
        compute_u(wA, x, b0, n0 + nl + 2, uA);
        logits_to_lds(uA, vv, lmat[0], j, p);
      }
      __syncthreads();
#pragma unroll
      for (int b = 0; b < BG; ++b) s[b] += uB[b] * cmat[1][b][j];
    }
  }

  const float scale = (PHASE == 0) ? (1.0f / 32.0f) : 1.0f;
#pragma unroll
  for (int b = 0; b < BG; ++b) {
    const size_t off =
        ((size_t)chunk * BB_ + (b0 + b)) * (JJ_ * DD_) + j * DD_ + 2 * p;
    *(float2*)&partial[off] = make_float2(s[b].x * scale, s[b].y * scale);
  }
}

// Reduce over chunks + squash. MODE 0: V = v ; 1: V += v ; 2: out = v.
// 256 blocks x 128 threads so every CU gets a block.
template <int MODE>
__global__ __launch_bounds__(128) void caps_reduce(
    const float* __restrict__ partial, float* __restrict__ V,
    float* __restrict__ out) {
  const int t = blockIdx.x * 128 + threadIdx.x;  // [0, B*J*D)
  float s = 0.f;
#pragma unroll 8
  for (int c = 0; c < NCHUNKS; ++c)
    s += partial[(size_t)c * (BB_ * JJ_ * DD_) + t];
  // sum of squares over d (16 consecutive lanes = one (b,j))
  float ss = s * s;
  ss += __shfl_xor(ss, 1);
  ss += __shfl_xor(ss, 2);
  ss += __shfl_xor(ss, 4);
  ss += __shfl_xor(ss, 8);
  const float v = s / sqrtf(ss + EPS_);
  if (MODE == 0)
    V[t] = v;
  else if (MODE == 1)
    V[t] += v;
  else
    out[t] = v;
}

extern "C" void kernel_launch(void* const* d_in, const int* in_sizes, int n_in,
                              void* d_out, int out_size, void* d_ws,
                              size_t ws_size, hipStream_t stream) {
  const float* x = (const float*)d_in[0];
  const float* W = (const float*)d_in[1];
  float* out = (float*)d_out;
  float* partial = (float*)d_ws;        // 16.8 MB
  float* V = partial + PARTIAL_FLOATS;  // 128 KB

  const dim3 kgrid(NBG * NCHUNKS);            // 1024 blocks x 256 threads
  const dim3 rgrid((BB_ * JJ_ * DD_) / 128);  // 256 blocks x 128 threads

  caps_phase<0><<<kgrid, 256, 0, stream>>>(x, W, nullptr, partial);
  caps_reduce<0><<<rgrid, 128, 0, stream>>>(partial, V, out);
  caps_phase<1><<<kgrid, 256, 0, stream>>>(x, W, V, partial);
  caps_reduce<1><<<rgrid, 128, 0, stream>>>(partial, V, out);
  caps_phase<2><<<kgrid, 256, 0, stream>>>(x, W, V, partial);
  caps_reduce<2><<<rgrid, 128, 0, stream>>>(partial, V, out);
}